// Round 9
// baseline (113.731 us; speedup 1.0000x reference)
//
#include <hip/hip_runtime.h>
#include <hip/hip_fp16.h>
#include <cstdint>
#include <cstddef>

#define IDIM 192
#define NSAMP 128
#define NRAYS 16384
#define NVOX (IDIM * IDIM * IDIM)   // 7077888

// Brick layout: 2x2x4 voxels = 16 entries x 4B = exactly one 64B cache line.
//   idx(x,y,z) = f(x) + g(y) + h(z)
//   f(x) = (x>>1)*73728 + (x&1)*8      (73728 = 96*48*16)
//   g(y) = (y>>1)*768   + (y&1)*4      (768   = 48*16)
//   h(z) = (z>>2)*16    + (z&3)

__device__ __forceinline__ uint32_t rotl32(uint32_t x, int r) {
    return (x << r) | (x >> (32 - r));
}

// JAX threefry2x32, key (0,1), partitionable path: bits(i) = x0 ^ x1 of TF((0,1),(0,i))
__device__ __forceinline__ uint32_t threefry_bits(uint32_t i) {
    const uint32_t ks0 = 0u;
    const uint32_t ks1 = 1u;
    const uint32_t ks2 = 0x1BD11BDAu ^ ks0 ^ ks1;  // 0x1BD11BDB
    uint32_t x0 = 0u + ks0;
    uint32_t x1 = i + ks1;
#define TF_ROUND(r) { x0 += x1; x1 = rotl32(x1, (r)); x1 ^= x0; }
    TF_ROUND(13) TF_ROUND(15) TF_ROUND(26) TF_ROUND(6)
    x0 += ks1; x1 += ks2 + 1u;
    TF_ROUND(17) TF_ROUND(29) TF_ROUND(16) TF_ROUND(24)
    x0 += ks2; x1 += ks0 + 2u;
    TF_ROUND(13) TF_ROUND(15) TF_ROUND(26) TF_ROUND(6)
    x0 += ks0; x1 += ks1 + 3u;
    TF_ROUND(17) TF_ROUND(29) TF_ROUND(16) TF_ROUND(24)
    x0 += ks1; x1 += ks2 + 4u;
    TF_ROUND(13) TF_ROUND(15) TF_ROUND(26) TF_ROUND(6)
    x0 += ks2; x1 += ks0 + 5u;
#undef TF_ROUND
    return x0 ^ x1;
}

// fuse: coalesced grid/opacity reads; brick-scattered 4B table writes
__global__ __launch_bounds__(256)
void fuse_kernel(const float* __restrict__ grid, const float* __restrict__ opacity,
                 __half2* __restrict__ tab) {
    __shared__ float sh[256 * 9];
    const int t = threadIdx.x;
    const int base = blockIdx.x * 256;
    const float* gp = grid + (size_t)base * 9;
    #pragma unroll
    for (int i = 0; i < 9; ++i) {
        sh[i * 256 + t] = gp[i * 256 + t];
    }
    __syncthreads();
    float s = 0.f;
    #pragma unroll
    for (int c = 0; c < 9; ++c) s += sh[t * 9 + c];
    const int v = base + t;
    const int xq = v / (IDIM * IDIM);
    const int rem = v - xq * (IDIM * IDIM);
    const int yq = rem / IDIM;
    const int zq = rem - yq * IDIM;
    const int idx = (xq >> 1) * 73728 + ((xq & 1) << 3)
                  + (yq >> 1) * 768   + ((yq & 1) << 2)
                  + (zq >> 2) * 16    + (zq & 3);
    tab[idx] = __floats2half2_rn(s, opacity[v]);
}

// One ray per WAVE; 2 waves per 128-thread block; no __syncthreads.
// Lane owns the consecutive sorted pair (2*lane, 2*lane+1): all 16 table
// loads issue in ONE burst (single L3 round-trip per wave), then a single
// pair-scan + reduction composites all 127 intervals.
__global__ __launch_bounds__(128)
void rf_kernel(const float* __restrict__ x, const float* __restrict__ d,
               const __half2* __restrict__ tab, float* __restrict__ out) {
    const int wave = threadIdx.x >> 6;
    const int lane = threadIdx.x & 63;
    const int r = blockIdx.x * 2 + wave;

    __shared__ __align__(16) float sv[2][NSAMP];  // unsorted, per wave
    __shared__ float st[2][NSAMP];                // sorted, per wave
    float* svw = sv[wave];
    float* stw = st[wave];

    // --- ray setup ---
    const float ox = x[r * 3 + 0], oy = x[r * 3 + 1], oz = x[r * 3 + 2];
    const float dx = d[r * 3 + 0], dy = d[r * 3 + 1], dz = d[r * 3 + 2];
    const float inv_dx = 1.f / dx, inv_dy = 1.f / dy, inv_dz = 1.f / dz;
    const float INF = 7077888.f;  // 192^3
    const float BMAX = (float)(IDIM - 1);

    float tmin = -INF, tmax = INF;
    {
        float t0 = (0.f - ox) * inv_dx, t1 = (BMAX - ox) * inv_dx;
        tmin = fmaxf(tmin, fminf(t0, t1)); tmax = fminf(tmax, fmaxf(t0, t1));
        t0 = (0.f - oy) * inv_dy; t1 = (BMAX - oy) * inv_dy;
        tmin = fmaxf(tmin, fminf(t0, t1)); tmax = fminf(tmax, fmaxf(t0, t1));
        t0 = (0.f - oz) * inv_dz; t1 = (BMAX - oz) * inv_dz;
        tmin = fmaxf(tmin, fminf(t0, t1)); tmax = fminf(tmax, fmaxf(t0, t1));
    }

    // --- JAX-exact uniforms: generate samples (lane) and (lane+64) ---
    const uint32_t i0 = (uint32_t)(r * NSAMP + lane);
    const uint32_t b0 = threefry_bits(i0);
    const uint32_t b1 = threefry_bits(i0 + 64u);
    float u0 = __uint_as_float((b0 >> 9) | 0x3f800000u) - 1.0f;
    float u1 = __uint_as_float((b1 >> 9) | 0x3f800000u) - 1.0f;
    u0 = fmaxf(0.f, u0);
    u1 = fmaxf(0.f, u1);
    const float v0 = tmin + u0 * (tmax - tmin);
    const float v1 = tmin + u1 * (tmax - tmin);
    svw[lane] = v0;
    svw[lane + 64] = v1;
    // wave-synchronous LDS: same-wave write->read needs no barrier

    // --- rank sort (2 ranks/thread, broadcast float4 reads) ---
    int r0 = 0, r1 = 0;
    const int s1i = lane + 64;
    #pragma unroll 4
    for (int j = 0; j < NSAMP; j += 4) {
        const float4 q = *reinterpret_cast<const float4*>(&svw[j]);
        r0 += (q.x < v0) | ((q.x == v0) & (j + 0 < lane));
        r0 += (q.y < v0) | ((q.y == v0) & (j + 1 < lane));
        r0 += (q.z < v0) | ((q.z == v0) & (j + 2 < lane));
        r0 += (q.w < v0) | ((q.w == v0) & (j + 3 < lane));
        r1 += (q.x < v1) | ((q.x == v1) & (j + 0 < s1i));
        r1 += (q.y < v1) | ((q.y == v1) & (j + 1 < s1i));
        r1 += (q.z < v1) | ((q.z == v1) & (j + 2 < s1i));
        r1 += (q.w < v1) | ((q.w == v1) & (j + 3 < s1i));
    }
    stw[r0] = v0;
    stw[r1] = v1;

    // --- read consecutive sorted pair; compute both address sets ---
    const int l2 = lane * 2;
    const float ts0 = stw[l2];
    const float ts1 = stw[l2 + 1];
    const float tn1 = stw[(l2 + 2 < NSAMP) ? l2 + 2 : NSAMP - 1];

    int idxA[8], idxB[8];
    float wA[8], wB[8];
    auto addrs = [&](float tpar, int* idx, float* w) {
        const float px = ox + tpar * dx;
        const float py = oy + tpar * dy;
        const float pz = oz + tpar * dz;
        int ix = (int)floorf(px); ix = ix < 0 ? 0 : (ix > IDIM - 2 ? IDIM - 2 : ix);
        int iy = (int)floorf(py); iy = iy < 0 ? 0 : (iy > IDIM - 2 ? IDIM - 2 : iy);
        int iz = (int)floorf(pz); iz = iz < 0 ? 0 : (iz > IDIM - 2 ? IDIM - 2 : iz);
        const float fx = px - (float)ix;
        const float fy = py - (float)iy;
        const float fz = pz - (float)iz;
        const float wx0 = 1.f - fx, wx1 = fx;
        const float wy0 = 1.f - fy, wy1 = fy;
        const float wz0 = 1.f - fz, wz1 = fz;
        w[0] = wx0 * wy0 * wz0; w[1] = wx0 * wy0 * wz1;
        w[2] = wx0 * wy1 * wz0; w[3] = wx0 * wy1 * wz1;
        w[4] = wx1 * wy0 * wz0; w[5] = wx1 * wy0 * wz1;
        w[6] = wx1 * wy1 * wz0; w[7] = wx1 * wy1 * wz1;
        const int f0 = (ix >> 1) * 73728 + ((ix & 1) << 3);
        const int f1 = ((ix + 1) >> 1) * 73728 + (((ix + 1) & 1) << 3);
        const int g0 = (iy >> 1) * 768 + ((iy & 1) << 2);
        const int g1 = ((iy + 1) >> 1) * 768 + (((iy + 1) & 1) << 2);
        const int h0 = (iz >> 2) * 16 + (iz & 3);
        const int h1 = ((iz + 1) >> 2) * 16 + ((iz + 1) & 3);
        idx[0] = f0 + g0 + h0; idx[1] = f0 + g0 + h1;
        idx[2] = f0 + g1 + h0; idx[3] = f0 + g1 + h1;
        idx[4] = f1 + g0 + h0; idx[5] = f1 + g0 + h1;
        idx[6] = f1 + g1 + h0; idx[7] = f1 + g1 + h1;
    };
    addrs(ts0, idxA, wA);
    addrs(ts1, idxB, wB);

    // --- ONE load burst: 16 outstanding 4B loads, single wait ---
    __half2 a[8], b[8];
    #pragma unroll
    for (int j = 0; j < 8; ++j) a[j] = tab[idxA[j]];
    #pragma unroll
    for (int j = 0; j < 8; ++j) b[j] = tab[idxB[j]];

    float hsv0 = 0.f, opv0 = 0.f, hsv1 = 0.f, opv1 = 0.f;
    #pragma unroll
    for (int j = 0; j < 8; ++j) {
        const float2 ca = __half22float2(a[j]);
        const float2 cb = __half22float2(b[j]);
        hsv0 += wA[j] * ca.x; opv0 += wA[j] * ca.y;
        hsv1 += wB[j] * cb.x; opv1 += wB[j] * cb.y;
    }

    // --- compositing: pair-scan over 64 lanes covers all 127 intervals ---
    const float cur0 = (ts1 - ts0) * opv0;
    const float cur1 = (lane < 63) ? (tn1 - ts1) * opv1 : 0.f;
    const float pair = cur0 + cur1;

    float incl = pair;
    #pragma unroll
    for (int off = 1; off < 64; off <<= 1) {
        const float tmp = __shfl_up(incl, off);
        if (lane >= off) incl += tmp;
    }
    const float excl0 = incl - pair;
    const float excl1 = excl0 + cur0;

    const float color0 = 1.f / (1.f + __expf(-hsv0));
    float contrib = __expf(-excl0) * (1.f - __expf(-cur0)) * color0;
    if (lane < 63) {
        const float color1 = 1.f / (1.f + __expf(-hsv1));
        contrib += __expf(-excl1) * (1.f - __expf(-cur1)) * color1;
    }

    // --- wave reduction ---
    #pragma unroll
    for (int off = 32; off > 0; off >>= 1) contrib += __shfl_down(contrib, off);
    if (lane == 0) out[r] = contrib;
}

extern "C" void kernel_launch(void* const* d_in, const int* in_sizes, int n_in,
                              void* d_out, int out_size, void* d_ws, size_t ws_size,
                              hipStream_t stream) {
    const float* x       = (const float*)d_in[0];
    const float* d       = (const float*)d_in[1];
    const float* grid    = (const float*)d_in[2];
    const float* opacity = (const float*)d_in[3];
    float* out = (float*)d_out;

    fuse_kernel<<<NVOX / 256, 256, 0, stream>>>(grid, opacity, (__half2*)d_ws);
    rf_kernel<<<NRAYS / 2, 128, 0, stream>>>(x, d, (const __half2*)d_ws, out);
}

// Round 10
// 98.715 us; speedup vs baseline: 1.1521x; 1.1521x over previous
//
#include <hip/hip_runtime.h>
#include <hip/hip_fp16.h>
#include <cstdint>
#include <cstddef>

#define IDIM 192
#define NSAMP 128
#define NRAYS 16384
#define NVOX (IDIM * IDIM * IDIM)   // 7077888

// Brick layout: 2x2x4 voxels = 16 entries x 4B = exactly one 64B cache line.
//   idx(x,y,z) = f(x) + g(y) + h(z)
//   f(x) = (x>>1)*73728 + (x&1)*8      (73728 = 96*48*16)
//   g(y) = (y>>1)*768   + (y&1)*4      (768   = 48*16)
//   h(z) = (z>>2)*16    + (z&3)

__device__ __forceinline__ uint32_t rotl32(uint32_t x, int r) {
    return (x << r) | (x >> (32 - r));
}

// JAX threefry2x32, key (0,1), partitionable path: bits(i) = x0 ^ x1 of TF((0,1),(0,i))
__device__ __forceinline__ uint32_t threefry_bits(uint32_t i) {
    const uint32_t ks0 = 0u;
    const uint32_t ks1 = 1u;
    const uint32_t ks2 = 0x1BD11BDAu ^ ks0 ^ ks1;  // 0x1BD11BDB
    uint32_t x0 = 0u + ks0;
    uint32_t x1 = i + ks1;
#define TF_ROUND(r) { x0 += x1; x1 = rotl32(x1, (r)); x1 ^= x0; }
    TF_ROUND(13) TF_ROUND(15) TF_ROUND(26) TF_ROUND(6)
    x0 += ks1; x1 += ks2 + 1u;
    TF_ROUND(17) TF_ROUND(29) TF_ROUND(16) TF_ROUND(24)
    x0 += ks2; x1 += ks0 + 2u;
    TF_ROUND(13) TF_ROUND(15) TF_ROUND(26) TF_ROUND(6)
    x0 += ks0; x1 += ks1 + 3u;
    TF_ROUND(17) TF_ROUND(29) TF_ROUND(16) TF_ROUND(24)
    x0 += ks1; x1 += ks2 + 4u;
    TF_ROUND(13) TF_ROUND(15) TF_ROUND(26) TF_ROUND(6)
    x0 += ks2; x1 += ks0 + 5u;
#undef TF_ROUND
    return x0 ^ x1;
}

// fuse: coalesced grid/opacity reads; brick-scattered 4B table writes
__global__ __launch_bounds__(256)
void fuse_kernel(const float* __restrict__ grid, const float* __restrict__ opacity,
                 __half2* __restrict__ tab) {
    __shared__ float sh[256 * 9];
    const int t = threadIdx.x;
    const int base = blockIdx.x * 256;
    const float* gp = grid + (size_t)base * 9;
    #pragma unroll
    for (int i = 0; i < 9; ++i) {
        sh[i * 256 + t] = gp[i * 256 + t];
    }
    __syncthreads();
    float s = 0.f;
    #pragma unroll
    for (int c = 0; c < 9; ++c) s += sh[t * 9 + c];
    const int v = base + t;
    const int xq = v / (IDIM * IDIM);
    const int rem = v - xq * (IDIM * IDIM);
    const int yq = rem / IDIM;
    const int zq = rem - yq * IDIM;
    const int idx = (xq >> 1) * 73728 + ((xq & 1) << 3)
                  + (yq >> 1) * 768   + ((yq & 1) << 2)
                  + (zq >> 2) * 16    + (zq & 3);
    tab[idx] = __floats2half2_rn(s, opacity[v]);
}

// One ray per WAVE; 2 waves (rays) per 128-thread block; no __syncthreads.
// Round 1 composites sorted samples 0..63; round 2 (64..126) is skipped
// when transmittance is already < e^-10 (wave-uniform branch).
// __launch_bounds__(128, 8): cap VGPR<=64 -> 32 waves/CU for max TLP over gathers.
__global__ __launch_bounds__(128, 8)
void rf_kernel(const float* __restrict__ x, const float* __restrict__ d,
               const __half2* __restrict__ tab, float* __restrict__ out) {
    const int wave = threadIdx.x >> 6;
    const int lane = threadIdx.x & 63;
    const int r = blockIdx.x * 2 + wave;

    __shared__ __align__(16) float sv[2][NSAMP];  // unsorted, per wave
    __shared__ float st[2][NSAMP];                // sorted, per wave
    float* svw = sv[wave];
    float* stw = st[wave];

    // --- ray setup ---
    const float ox = x[r * 3 + 0], oy = x[r * 3 + 1], oz = x[r * 3 + 2];
    const float dx = d[r * 3 + 0], dy = d[r * 3 + 1], dz = d[r * 3 + 2];
    const float inv_dx = 1.f / dx, inv_dy = 1.f / dy, inv_dz = 1.f / dz;
    const float INF = 7077888.f;  // 192^3
    const float BMAX = (float)(IDIM - 1);

    float tmin = -INF, tmax = INF;
    {
        float t0 = (0.f - ox) * inv_dx, t1 = (BMAX - ox) * inv_dx;
        tmin = fmaxf(tmin, fminf(t0, t1)); tmax = fminf(tmax, fmaxf(t0, t1));
        t0 = (0.f - oy) * inv_dy; t1 = (BMAX - oy) * inv_dy;
        tmin = fmaxf(tmin, fminf(t0, t1)); tmax = fminf(tmax, fmaxf(t0, t1));
        t0 = (0.f - oz) * inv_dz; t1 = (BMAX - oz) * inv_dz;
        tmin = fmaxf(tmin, fminf(t0, t1)); tmax = fminf(tmax, fmaxf(t0, t1));
    }

    // --- JAX-exact uniforms: this thread owns samples (lane) and (lane+64) ---
    const uint32_t i0 = (uint32_t)(r * NSAMP + lane);
    const uint32_t b0 = threefry_bits(i0);
    const uint32_t b1 = threefry_bits(i0 + 64u);
    float u0 = __uint_as_float((b0 >> 9) | 0x3f800000u) - 1.0f;
    float u1 = __uint_as_float((b1 >> 9) | 0x3f800000u) - 1.0f;
    u0 = fmaxf(0.f, u0);
    u1 = fmaxf(0.f, u1);
    const float v0 = tmin + u0 * (tmax - tmin);
    const float v1 = tmin + u1 * (tmax - tmin);
    svw[lane] = v0;
    svw[lane + 64] = v1;
    // wave-synchronous LDS: same-wave write->read, no barrier needed

    // --- rank sort (2 ranks/thread, broadcast float4 reads) ---
    int r0 = 0, r1 = 0;
    const int s1i = lane + 64;
    #pragma unroll 4
    for (int j = 0; j < NSAMP; j += 4) {
        const float4 q = *reinterpret_cast<const float4*>(&svw[j]);
        r0 += (q.x < v0) | ((q.x == v0) & (j + 0 < lane));
        r0 += (q.y < v0) | ((q.y == v0) & (j + 1 < lane));
        r0 += (q.z < v0) | ((q.z == v0) & (j + 2 < lane));
        r0 += (q.w < v0) | ((q.w == v0) & (j + 3 < lane));
        r1 += (q.x < v1) | ((q.x == v1) & (j + 0 < s1i));
        r1 += (q.y < v1) | ((q.y == v1) & (j + 1 < s1i));
        r1 += (q.z < v1) | ((q.z == v1) & (j + 2 < s1i));
        r1 += (q.w < v1) | ((q.w == v1) & (j + 3 < s1i));
    }
    stw[r0] = v0;
    stw[r1] = v1;

    // trilinear gather from bricked table
    auto sample_tab = [&](float tpar, float& hsv, float& opv) {
        const float px = ox + tpar * dx;
        const float py = oy + tpar * dy;
        const float pz = oz + tpar * dz;
        int ix = (int)floorf(px); ix = ix < 0 ? 0 : (ix > IDIM - 2 ? IDIM - 2 : ix);
        int iy = (int)floorf(py); iy = iy < 0 ? 0 : (iy > IDIM - 2 ? IDIM - 2 : iy);
        int iz = (int)floorf(pz); iz = iz < 0 ? 0 : (iz > IDIM - 2 ? IDIM - 2 : iz);
        const float fx = px - (float)ix;
        const float fy = py - (float)iy;
        const float fz = pz - (float)iz;
        const float wx0 = 1.f - fx, wx1 = fx;
        const float wy0 = 1.f - fy, wy1 = fy;
        const float wz0 = 1.f - fz, wz1 = fz;
        const float w000 = wx0 * wy0 * wz0, w001 = wx0 * wy0 * wz1;
        const float w010 = wx0 * wy1 * wz0, w011 = wx0 * wy1 * wz1;
        const float w100 = wx1 * wy0 * wz0, w101 = wx1 * wy0 * wz1;
        const float w110 = wx1 * wy1 * wz0, w111 = wx1 * wy1 * wz1;
        const int f0 = (ix >> 1) * 73728 + ((ix & 1) << 3);
        const int f1 = ((ix + 1) >> 1) * 73728 + (((ix + 1) & 1) << 3);
        const int g0 = (iy >> 1) * 768 + ((iy & 1) << 2);
        const int g1 = ((iy + 1) >> 1) * 768 + (((iy + 1) & 1) << 2);
        const int h0 = (iz >> 2) * 16 + (iz & 3);
        const int h1 = ((iz + 1) >> 2) * 16 + ((iz + 1) & 3);
        const float2 c000 = __half22float2(tab[f0 + g0 + h0]);
        const float2 c001 = __half22float2(tab[f0 + g0 + h1]);
        const float2 c010 = __half22float2(tab[f0 + g1 + h0]);
        const float2 c011 = __half22float2(tab[f0 + g1 + h1]);
        const float2 c100 = __half22float2(tab[f1 + g0 + h0]);
        const float2 c101 = __half22float2(tab[f1 + g0 + h1]);
        const float2 c110 = __half22float2(tab[f1 + g1 + h0]);
        const float2 c111 = __half22float2(tab[f1 + g1 + h1]);
        hsv = w000 * c000.x + w001 * c001.x + w010 * c010.x + w011 * c011.x +
              w100 * c100.x + w101 * c101.x + w110 * c110.x + w111 * c111.x;
        opv = w000 * c000.y + w001 * c001.y + w010 * c010.y + w011 * c011.y +
              w100 * c100.y + w101 * c101.y + w110 * c110.y + w111 * c111.y;
    };

    // ---- Round 1: samples 0..63 (all lanes active) ----
    const float ts = stw[lane];
    const float tn = stw[lane + 1];
    float hsv, opv;
    sample_tab(ts, hsv, opv);
    const float cur = (tn - ts) * opv;

    float incl = cur;
    #pragma unroll
    for (int off = 1; off < 64; off <<= 1) {
        const float tmp = __shfl_up(incl, off);
        if (lane >= off) incl += tmp;
    }
    const float excl = incl - cur;
    const float color = 1.f / (1.f + __expf(-hsv));
    float contrib = __expf(-excl) * (1.f - __expf(-cur)) * color;

    float red = contrib;
    #pragma unroll
    for (int off = 32; off > 0; off >>= 1) red += __shfl_down(red, off);
    float total = red;  // valid on lane 0

    const float cum64 = __shfl(incl, 63);

    // ---- Round 2: samples 64..126, only if transmittance still matters ----
    if (cum64 < 10.f) {
        const bool act = lane < 63;
        const int s2 = lane + 64;
        const float ts2 = stw[act ? s2 : 126];
        const float tn2 = stw[act ? s2 + 1 : 127];
        float hsv2, opv2;
        sample_tab(ts2, hsv2, opv2);
        const float cur2 = act ? (tn2 - ts2) * opv2 : 0.f;

        float incl2 = cur2;
        #pragma unroll
        for (int off = 1; off < 64; off <<= 1) {
            const float tmp = __shfl_up(incl2, off);
            if (lane >= off) incl2 += tmp;
        }
        const float excl2 = cum64 + (incl2 - cur2);
        const float color2 = 1.f / (1.f + __expf(-hsv2));
        float c2 = act ? __expf(-excl2) * (1.f - __expf(-cur2)) * color2 : 0.f;
        #pragma unroll
        for (int off = 32; off > 0; off >>= 1) c2 += __shfl_down(c2, off);
        total += c2;
    }

    if (lane == 0) out[r] = total;
}

extern "C" void kernel_launch(void* const* d_in, const int* in_sizes, int n_in,
                              void* d_out, int out_size, void* d_ws, size_t ws_size,
                              hipStream_t stream) {
    const float* x       = (const float*)d_in[0];
    const float* d       = (const float*)d_in[1];
    const float* grid    = (const float*)d_in[2];
    const float* opacity = (const float*)d_in[3];
    float* out = (float*)d_out;

    fuse_kernel<<<NVOX / 256, 256, 0, stream>>>(grid, opacity, (__half2*)d_ws);
    rf_kernel<<<NRAYS / 2, 128, 0, stream>>>(x, d, (const __half2*)d_ws, out);
}

// Round 11
// 98.590 us; speedup vs baseline: 1.1536x; 1.0013x over previous
//
#include <hip/hip_runtime.h>
#include <hip/hip_fp16.h>
#include <cstdint>
#include <cstddef>

#define IDIM 192
#define NSAMP 128
#define NRAYS 16384
#define NVOX (IDIM * IDIM * IDIM)   // 7077888
#define SPAD (NSAMP + 4)            // +4 floats: distinct banks for the two halves

// Brick layout: 2x2x4 voxels = 16 entries x 4B = exactly one 64B cache line.
//   idx(x,y,z) = f(x) + g(y) + h(z)
//   f(x) = (x>>1)*73728 + (x&1)*8      (73728 = 96*48*16)
//   g(y) = (y>>1)*768   + (y&1)*4      (768   = 48*16)
//   h(z) = (z>>2)*16    + (z&3)

__device__ __forceinline__ uint32_t rotl32(uint32_t x, int r) {
    return (x << r) | (x >> (32 - r));
}

// JAX threefry2x32, key (0,1), partitionable path: bits(i) = x0 ^ x1 of TF((0,1),(0,i))
__device__ __forceinline__ uint32_t threefry_bits(uint32_t i) {
    const uint32_t ks0 = 0u;
    const uint32_t ks1 = 1u;
    const uint32_t ks2 = 0x1BD11BDAu ^ ks0 ^ ks1;  // 0x1BD11BDB
    uint32_t x0 = 0u + ks0;
    uint32_t x1 = i + ks1;
#define TF_ROUND(r) { x0 += x1; x1 = rotl32(x1, (r)); x1 ^= x0; }
    TF_ROUND(13) TF_ROUND(15) TF_ROUND(26) TF_ROUND(6)
    x0 += ks1; x1 += ks2 + 1u;
    TF_ROUND(17) TF_ROUND(29) TF_ROUND(16) TF_ROUND(24)
    x0 += ks2; x1 += ks0 + 2u;
    TF_ROUND(13) TF_ROUND(15) TF_ROUND(26) TF_ROUND(6)
    x0 += ks0; x1 += ks1 + 3u;
    TF_ROUND(17) TF_ROUND(29) TF_ROUND(16) TF_ROUND(24)
    x0 += ks1; x1 += ks2 + 4u;
    TF_ROUND(13) TF_ROUND(15) TF_ROUND(26) TF_ROUND(6)
    x0 += ks2; x1 += ks0 + 5u;
#undef TF_ROUND
    return x0 ^ x1;
}

// fuse: coalesced grid/opacity reads; brick-scattered 4B table writes
__global__ __launch_bounds__(256)
void fuse_kernel(const float* __restrict__ grid, const float* __restrict__ opacity,
                 __half2* __restrict__ tab) {
    __shared__ float sh[256 * 9];
    const int t = threadIdx.x;
    const int base = blockIdx.x * 256;
    const float* gp = grid + (size_t)base * 9;
    #pragma unroll
    for (int i = 0; i < 9; ++i) {
        sh[i * 256 + t] = gp[i * 256 + t];
    }
    __syncthreads();
    float s = 0.f;
    #pragma unroll
    for (int c = 0; c < 9; ++c) s += sh[t * 9 + c];
    const int v = base + t;
    const int xq = v / (IDIM * IDIM);
    const int rem = v - xq * (IDIM * IDIM);
    const int yq = rem / IDIM;
    const int zq = rem - yq * IDIM;
    const int idx = (xq >> 1) * 73728 + ((xq & 1) << 3)
                  + (yq >> 1) * 768   + ((yq & 1) << 2)
                  + (zq >> 2) * 16    + (zq & 3);
    tab[idx] = __floats2half2_rn(s, opacity[v]);
}

// TWO rays per wave (32 lanes each), 4 rays per 128-thread block.
// Composite in rounds of 32 sorted samples; a half-wave whose cumulative
// opacity exceeds 10 stops gathering (exec-mask suppresses its transactions).
__global__ __launch_bounds__(128, 8)
void rf_kernel(const float* __restrict__ x, const float* __restrict__ d,
               const __half2* __restrict__ tab, float* __restrict__ out) {
    const int wave = threadIdx.x >> 6;
    const int lane = threadIdx.x & 63;
    const int half = lane >> 5;       // which ray within the wave
    const int hl   = lane & 31;       // lane within the ray
    const int r = blockIdx.x * 4 + wave * 2 + half;

    __shared__ __align__(16) float sv[2][2][SPAD];  // unsorted, per wave/half
    __shared__ __align__(16) float st[2][2][SPAD];  // sorted
    float* svw = sv[wave][half];
    float* stw = st[wave][half];

    // --- ray setup ---
    const float ox = x[r * 3 + 0], oy = x[r * 3 + 1], oz = x[r * 3 + 2];
    const float dx = d[r * 3 + 0], dy = d[r * 3 + 1], dz = d[r * 3 + 2];
    const float inv_dx = 1.f / dx, inv_dy = 1.f / dy, inv_dz = 1.f / dz;
    const float INF = 7077888.f;  // 192^3
    const float BMAX = (float)(IDIM - 1);

    float tmin = -INF, tmax = INF;
    {
        float t0 = (0.f - ox) * inv_dx, t1 = (BMAX - ox) * inv_dx;
        tmin = fmaxf(tmin, fminf(t0, t1)); tmax = fminf(tmax, fmaxf(t0, t1));
        t0 = (0.f - oy) * inv_dy; t1 = (BMAX - oy) * inv_dy;
        tmin = fmaxf(tmin, fminf(t0, t1)); tmax = fminf(tmax, fmaxf(t0, t1));
        t0 = (0.f - oz) * inv_dz; t1 = (BMAX - oz) * inv_dz;
        tmin = fmaxf(tmin, fminf(t0, t1)); tmax = fminf(tmax, fmaxf(t0, t1));
    }

    // --- JAX-exact uniforms: thread owns its ray's samples hl+32m, m=0..3 ---
    float vs[4];
    #pragma unroll
    for (int m = 0; m < 4; ++m) {
        const uint32_t i = (uint32_t)(r * NSAMP + hl + 32 * m);
        const uint32_t b = threefry_bits(i);
        float u = __uint_as_float((b >> 9) | 0x3f800000u) - 1.0f;
        u = fmaxf(0.f, u);
        vs[m] = tmin + u * (tmax - tmin);
        svw[hl + 32 * m] = vs[m];
    }
    // wave-synchronous LDS: same-wave write->read needs no barrier

    // --- rank sort: 4 ranks/thread vs own ray's 128 (broadcast float4 reads) ---
    int rk[4] = {0, 0, 0, 0};
    #pragma unroll 4
    for (int j = 0; j < NSAMP; j += 4) {
        const float4 q = *reinterpret_cast<const float4*>(&svw[j]);
        #pragma unroll
        for (int m = 0; m < 4; ++m) {
            const int sm = hl + 32 * m;
            rk[m] += (q.x < vs[m]) | ((q.x == vs[m]) & (j + 0 < sm));
            rk[m] += (q.y < vs[m]) | ((q.y == vs[m]) & (j + 1 < sm));
            rk[m] += (q.z < vs[m]) | ((q.z == vs[m]) & (j + 2 < sm));
            rk[m] += (q.w < vs[m]) | ((q.w == vs[m]) & (j + 3 < sm));
        }
    }
    #pragma unroll
    for (int m = 0; m < 4; ++m) stw[rk[m]] = vs[m];

    // trilinear gather from bricked table
    auto sample_tab = [&](float tpar, float& hsv, float& opv) {
        const float px = ox + tpar * dx;
        const float py = oy + tpar * dy;
        const float pz = oz + tpar * dz;
        int ix = (int)floorf(px); ix = ix < 0 ? 0 : (ix > IDIM - 2 ? IDIM - 2 : ix);
        int iy = (int)floorf(py); iy = iy < 0 ? 0 : (iy > IDIM - 2 ? IDIM - 2 : iy);
        int iz = (int)floorf(pz); iz = iz < 0 ? 0 : (iz > IDIM - 2 ? IDIM - 2 : iz);
        const float fx = px - (float)ix;
        const float fy = py - (float)iy;
        const float fz = pz - (float)iz;
        const float wx0 = 1.f - fx, wx1 = fx;
        const float wy0 = 1.f - fy, wy1 = fy;
        const float wz0 = 1.f - fz, wz1 = fz;
        const float w000 = wx0 * wy0 * wz0, w001 = wx0 * wy0 * wz1;
        const float w010 = wx0 * wy1 * wz0, w011 = wx0 * wy1 * wz1;
        const float w100 = wx1 * wy0 * wz0, w101 = wx1 * wy0 * wz1;
        const float w110 = wx1 * wy1 * wz0, w111 = wx1 * wy1 * wz1;
        const int f0 = (ix >> 1) * 73728 + ((ix & 1) << 3);
        const int f1 = ((ix + 1) >> 1) * 73728 + (((ix + 1) & 1) << 3);
        const int g0 = (iy >> 1) * 768 + ((iy & 1) << 2);
        const int g1 = ((iy + 1) >> 1) * 768 + (((iy + 1) & 1) << 2);
        const int h0 = (iz >> 2) * 16 + (iz & 3);
        const int h1 = ((iz + 1) >> 2) * 16 + ((iz + 1) & 3);
        const float2 c000 = __half22float2(tab[f0 + g0 + h0]);
        const float2 c001 = __half22float2(tab[f0 + g0 + h1]);
        const float2 c010 = __half22float2(tab[f0 + g1 + h0]);
        const float2 c011 = __half22float2(tab[f0 + g1 + h1]);
        const float2 c100 = __half22float2(tab[f1 + g0 + h0]);
        const float2 c101 = __half22float2(tab[f1 + g0 + h1]);
        const float2 c110 = __half22float2(tab[f1 + g1 + h0]);
        const float2 c111 = __half22float2(tab[f1 + g1 + h1]);
        hsv = w000 * c000.x + w001 * c001.x + w010 * c010.x + w011 * c011.x +
              w100 * c100.x + w101 * c101.x + w110 * c110.x + w111 * c111.x;
        opv = w000 * c000.y + w001 * c001.y + w010 * c010.y + w011 * c011.y +
              w100 * c100.y + w101 * c101.y + w110 * c110.y + w111 * c111.y;
    };

    // --- composite in rounds of 32 samples; per-half early exit ---
    float cumRay = 0.f;
    float acc = 0.f;
    bool act = true;
    for (int k = 0; k < 4; ++k) {
        const int s = k * 32 + hl;
        float cur = 0.f, hsv = 0.f, opv = 0.f;
        if (act) {
            const float ts = stw[s];
            const float tn = stw[(s < NSAMP - 1) ? s + 1 : NSAMP - 1];
            if (s < NSAMP - 1) {
                sample_tab(ts, hsv, opv);
                cur = (tn - ts) * opv;
            }
        }
        // 32-lane inclusive scan within the half (guard keeps it in-half)
        float incl = cur;
        #pragma unroll
        for (int off = 1; off < 32; off <<= 1) {
            const float tmp = __shfl_up(incl, off);
            if (hl >= off) incl += tmp;
        }
        if (act && (s < NSAMP - 1)) {
            const float excl = cumRay + incl - cur;
            const float color = 1.f / (1.f + __expf(-hsv));
            acc += __expf(-excl) * (1.f - __expf(-cur)) * color;
        }
        const float roundSum = __shfl(incl, (half << 5) + 31);
        cumRay += roundSum;
        act = act && (cumRay < 10.f);
        if (!__any(act)) break;
    }

    // --- 32-lane reduction within the half ---
    #pragma unroll
    for (int off = 16; off > 0; off >>= 1) acc += __shfl_down(acc, off);
    if (hl == 0) out[r] = acc;
}

extern "C" void kernel_launch(void* const* d_in, const int* in_sizes, int n_in,
                              void* d_out, int out_size, void* d_ws, size_t ws_size,
                              hipStream_t stream) {
    const float* x       = (const float*)d_in[0];
    const float* d       = (const float*)d_in[1];
    const float* grid    = (const float*)d_in[2];
    const float* opacity = (const float*)d_in[3];
    float* out = (float*)d_out;

    fuse_kernel<<<NVOX / 256, 256, 0, stream>>>(grid, opacity, (__half2*)d_ws);
    rf_kernel<<<NRAYS / 4, 128, 0, stream>>>(x, d, (const __half2*)d_ws, out);
}

// Round 12
// 79.164 us; speedup vs baseline: 1.4366x; 1.2454x over previous
//
#include <hip/hip_runtime.h>
#include <hip/hip_fp16.h>
#include <cstdint>
#include <cstddef>

#define IDIM 192
#define NSAMP 128
#define NRAYS 16384
#define NVOX (IDIM * IDIM * IDIM)   // 7077888

// Brick layout: 2x2x4 voxels = 16 entries x 4B = exactly one 64B cache line.
//   idx(x,y,z) = f(x) + g(y) + h(z)
//   f(x) = (x>>1)*73728 + (x&1)*8      (73728 = 96*48*16)
//   g(y) = (y>>1)*768   + (y&1)*4      (768   = 48*16)
//   h(z) = (z>>2)*16    + (z&3)

__device__ __forceinline__ uint32_t rotl32(uint32_t x, int r) {
    return (x << r) | (x >> (32 - r));
}

// JAX threefry2x32, key (0,1), partitionable path: bits(i) = x0 ^ x1 of TF((0,1),(0,i))
__device__ __forceinline__ uint32_t threefry_bits(uint32_t i) {
    const uint32_t ks0 = 0u;
    const uint32_t ks1 = 1u;
    const uint32_t ks2 = 0x1BD11BDAu ^ ks0 ^ ks1;  // 0x1BD11BDB
    uint32_t x0 = 0u + ks0;
    uint32_t x1 = i + ks1;
#define TF_ROUND(r) { x0 += x1; x1 = rotl32(x1, (r)); x1 ^= x0; }
    TF_ROUND(13) TF_ROUND(15) TF_ROUND(26) TF_ROUND(6)
    x0 += ks1; x1 += ks2 + 1u;
    TF_ROUND(17) TF_ROUND(29) TF_ROUND(16) TF_ROUND(24)
    x0 += ks2; x1 += ks0 + 2u;
    TF_ROUND(13) TF_ROUND(15) TF_ROUND(26) TF_ROUND(6)
    x0 += ks0; x1 += ks1 + 3u;
    TF_ROUND(17) TF_ROUND(29) TF_ROUND(16) TF_ROUND(24)
    x0 += ks1; x1 += ks2 + 4u;
    TF_ROUND(13) TF_ROUND(15) TF_ROUND(26) TF_ROUND(6)
    x0 += ks2; x1 += ks0 + 5u;
#undef TF_ROUND
    return x0 ^ x1;
}

// fuse: coalesced grid/opacity reads; brick-scattered 4B table writes
__global__ __launch_bounds__(256)
void fuse_kernel(const float* __restrict__ grid, const float* __restrict__ opacity,
                 __half2* __restrict__ tab) {
    __shared__ float sh[256 * 9];
    const int t = threadIdx.x;
    const int base = blockIdx.x * 256;
    const float* gp = grid + (size_t)base * 9;
    #pragma unroll
    for (int i = 0; i < 9; ++i) {
        sh[i * 256 + t] = gp[i * 256 + t];
    }
    __syncthreads();
    float s = 0.f;
    #pragma unroll
    for (int c = 0; c < 9; ++c) s += sh[t * 9 + c];
    const int v = base + t;
    const int xq = v / (IDIM * IDIM);
    const int rem = v - xq * (IDIM * IDIM);
    const int yq = rem / IDIM;
    const int zq = rem - yq * IDIM;
    const int idx = (xq >> 1) * 73728 + ((xq & 1) << 3)
                  + (yq >> 1) * 768   + ((yq & 1) << 2)
                  + (zq >> 2) * 16    + (zq & 3);
    tab[idx] = __floats2half2_rn(s, opacity[v]);
}

// One ray per WAVE; 2 waves (rays) per 128-thread block; ZERO LDS.
// 128 samples live in 2 regs/lane (element e = lane + 64*reg); full wave-
// bitonic sort via shfl_xor (27 inter-lane + 1 intra-thread steps).
// Round 1 composites sorted samples 0..63; round 2 (64..126) is skipped
// when cumulative opacity already exceeds 10 (wave-uniform branch).
__global__ __launch_bounds__(128, 8)
void rf_kernel(const float* __restrict__ x, const float* __restrict__ d,
               const __half2* __restrict__ tab, float* __restrict__ out) {
    const int wave = threadIdx.x >> 6;
    const int lane = threadIdx.x & 63;
    const int r = blockIdx.x * 2 + wave;

    // --- ray setup ---
    const float ox = x[r * 3 + 0], oy = x[r * 3 + 1], oz = x[r * 3 + 2];
    const float dx = d[r * 3 + 0], dy = d[r * 3 + 1], dz = d[r * 3 + 2];
    const float inv_dx = 1.f / dx, inv_dy = 1.f / dy, inv_dz = 1.f / dz;
    const float INF = 7077888.f;  // 192^3
    const float BMAX = (float)(IDIM - 1);

    float tmin = -INF, tmax = INF;
    {
        float t0 = (0.f - ox) * inv_dx, t1 = (BMAX - ox) * inv_dx;
        tmin = fmaxf(tmin, fminf(t0, t1)); tmax = fminf(tmax, fmaxf(t0, t1));
        t0 = (0.f - oy) * inv_dy; t1 = (BMAX - oy) * inv_dy;
        tmin = fmaxf(tmin, fminf(t0, t1)); tmax = fminf(tmax, fmaxf(t0, t1));
        t0 = (0.f - oz) * inv_dz; t1 = (BMAX - oz) * inv_dz;
        tmin = fmaxf(tmin, fminf(t0, t1)); tmax = fminf(tmax, fmaxf(t0, t1));
    }

    // --- JAX-exact uniforms: this thread owns samples (lane) and (lane+64) ---
    const uint32_t i0 = (uint32_t)(r * NSAMP + lane);
    const uint32_t b0 = threefry_bits(i0);
    const uint32_t b1 = threefry_bits(i0 + 64u);
    float u0 = __uint_as_float((b0 >> 9) | 0x3f800000u) - 1.0f;
    float u1 = __uint_as_float((b1 >> 9) | 0x3f800000u) - 1.0f;
    u0 = fmaxf(0.f, u0);
    u1 = fmaxf(0.f, u1);
    float v0 = tmin + u0 * (tmax - tmin);
    float v1 = tmin + u1 * (tmax - tmin);

    // --- in-register wave-bitonic sort of 128 values (ascending) ---
    // element id: e0 = lane (v0), e1 = lane + 64 (v1)
#define BSTEP(J, K)                                                            \
    {                                                                          \
        const float p0 = __shfl_xor(v0, (J));                                  \
        const float p1 = __shfl_xor(v1, (J));                                  \
        const bool lower = (lane & (J)) == 0;                                  \
        const bool tm0 = (((lane) & (K)) == 0) == lower;                       \
        const bool tm1 = ((((lane) + 64) & (K)) == 0) == lower;                \
        v0 = tm0 ? fminf(v0, p0) : fmaxf(v0, p0);                              \
        v1 = tm1 ? fminf(v1, p1) : fmaxf(v1, p1);                              \
    }
    #pragma unroll
    for (int k = 2; k <= 64; k <<= 1) {
        #pragma unroll
        for (int j = k >> 1; j >= 1; j >>= 1) BSTEP(j, k)
    }
    {   // k = 128, j = 64: intra-thread exchange (dir ascending everywhere)
        const float mn = fminf(v0, v1), mx = fmaxf(v0, v1);
        v0 = mn; v1 = mx;
    }
    #pragma unroll
    for (int j = 32; j >= 1; j >>= 1) BSTEP(j, 128)
#undef BSTEP
    // now v0 = sorted[lane], v1 = sorted[lane + 64]

    // trilinear gather from bricked table
    auto sample_tab = [&](float tpar, float& hsv, float& opv) {
        const float px = ox + tpar * dx;
        const float py = oy + tpar * dy;
        const float pz = oz + tpar * dz;
        int ix = (int)floorf(px); ix = ix < 0 ? 0 : (ix > IDIM - 2 ? IDIM - 2 : ix);
        int iy = (int)floorf(py); iy = iy < 0 ? 0 : (iy > IDIM - 2 ? IDIM - 2 : iy);
        int iz = (int)floorf(pz); iz = iz < 0 ? 0 : (iz > IDIM - 2 ? IDIM - 2 : iz);
        const float fx = px - (float)ix;
        const float fy = py - (float)iy;
        const float fz = pz - (float)iz;
        const float wx0 = 1.f - fx, wx1 = fx;
        const float wy0 = 1.f - fy, wy1 = fy;
        const float wz0 = 1.f - fz, wz1 = fz;
        const float w000 = wx0 * wy0 * wz0, w001 = wx0 * wy0 * wz1;
        const float w010 = wx0 * wy1 * wz0, w011 = wx0 * wy1 * wz1;
        const float w100 = wx1 * wy0 * wz0, w101 = wx1 * wy0 * wz1;
        const float w110 = wx1 * wy1 * wz0, w111 = wx1 * wy1 * wz1;
        const int f0 = (ix >> 1) * 73728 + ((ix & 1) << 3);
        const int f1 = ((ix + 1) >> 1) * 73728 + (((ix + 1) & 1) << 3);
        const int g0 = (iy >> 1) * 768 + ((iy & 1) << 2);
        const int g1 = ((iy + 1) >> 1) * 768 + (((iy + 1) & 1) << 2);
        const int h0 = (iz >> 2) * 16 + (iz & 3);
        const int h1 = ((iz + 1) >> 2) * 16 + ((iz + 1) & 3);
        const float2 c000 = __half22float2(tab[f0 + g0 + h0]);
        const float2 c001 = __half22float2(tab[f0 + g0 + h1]);
        const float2 c010 = __half22float2(tab[f0 + g1 + h0]);
        const float2 c011 = __half22float2(tab[f0 + g1 + h1]);
        const float2 c100 = __half22float2(tab[f1 + g0 + h0]);
        const float2 c101 = __half22float2(tab[f1 + g0 + h1]);
        const float2 c110 = __half22float2(tab[f1 + g1 + h0]);
        const float2 c111 = __half22float2(tab[f1 + g1 + h1]);
        hsv = w000 * c000.x + w001 * c001.x + w010 * c010.x + w011 * c011.x +
              w100 * c100.x + w101 * c101.x + w110 * c110.x + w111 * c111.x;
        opv = w000 * c000.y + w001 * c001.y + w010 * c010.y + w011 * c011.y +
              w100 * c100.y + w101 * c101.y + w110 * c110.y + w111 * c111.y;
    };

    // ---- Round 1: samples 0..63 (all lanes active; needs sorted[lane+1]) ----
    const float ts = v0;
    const float sd0 = __shfl_down(v0, 1);     // sorted[lane+1] for lane<63
    const float b64 = __shfl(v1, 0);          // sorted[64]
    const float tn = (lane < 63) ? sd0 : b64;

    float hsv, opv;
    sample_tab(ts, hsv, opv);
    const float cur = (tn - ts) * opv;

    float incl = cur;
    #pragma unroll
    for (int off = 1; off < 64; off <<= 1) {
        const float tmp = __shfl_up(incl, off);
        if (lane >= off) incl += tmp;
    }
    const float excl = incl - cur;
    const float color = 1.f / (1.f + __expf(-hsv));
    float contrib = __expf(-excl) * (1.f - __expf(-cur)) * color;

    float red = contrib;
    #pragma unroll
    for (int off = 32; off > 0; off >>= 1) red += __shfl_down(red, off);
    float total = red;  // valid on lane 0

    const float cum64 = __shfl(incl, 63);

    // ---- Round 2: samples 64..126, only if transmittance still matters ----
    if (cum64 < 10.f) {
        const bool act = lane < 63;           // intervals 64..126
        const float ts2 = v1;
        const float tn2 = __shfl_down(v1, 1); // sorted[lane+65] for lane<63
        float hsv2, opv2;
        sample_tab(ts2, hsv2, opv2);
        const float cur2 = act ? (tn2 - ts2) * opv2 : 0.f;

        float incl2 = cur2;
        #pragma unroll
        for (int off = 1; off < 64; off <<= 1) {
            const float tmp = __shfl_up(incl2, off);
            if (lane >= off) incl2 += tmp;
        }
        const float excl2 = cum64 + (incl2 - cur2);
        const float color2 = 1.f / (1.f + __expf(-hsv2));
        float c2 = act ? __expf(-excl2) * (1.f - __expf(-cur2)) * color2 : 0.f;
        #pragma unroll
        for (int off = 32; off > 0; off >>= 1) c2 += __shfl_down(c2, off);
        total += c2;
    }

    if (lane == 0) out[r] = total;
}

extern "C" void kernel_launch(void* const* d_in, const int* in_sizes, int n_in,
                              void* d_out, int out_size, void* d_ws, size_t ws_size,
                              hipStream_t stream) {
    const float* x       = (const float*)d_in[0];
    const float* d       = (const float*)d_in[1];
    const float* grid    = (const float*)d_in[2];
    const float* opacity = (const float*)d_in[3];
    float* out = (float*)d_out;

    fuse_kernel<<<NVOX / 256, 256, 0, stream>>>(grid, opacity, (__half2*)d_ws);
    rf_kernel<<<NRAYS / 2, 128, 0, stream>>>(x, d, (const __half2*)d_ws, out);
}

// Round 13
// 77.895 us; speedup vs baseline: 1.4601x; 1.0163x over previous
//
#include <hip/hip_runtime.h>
#include <hip/hip_fp16.h>
#include <cstdint>
#include <cstddef>

#define IDIM 192
#define NSAMP 128
#define NRAYS 16384
#define NVOX (IDIM * IDIM * IDIM)   // 7077888

// Brick layout: 2x2x4 voxels = 16 entries x 4B = exactly one 64B cache line.
//   idx(x,y,z) = f(x) + g(y) + h(z)
//   f(x) = (x>>1)*73728 + (x&1)*8      (73728 = 96*48*16)
//   g(y) = (y>>1)*768   + (y&1)*4      (768   = 48*16)
//   h(z) = (z>>2)*16    + (z&3)

__device__ __forceinline__ uint32_t rotl32(uint32_t x, int r) {
    return (x << r) | (x >> (32 - r));
}

// JAX threefry2x32, key (0,1), partitionable path: bits(i) = x0 ^ x1 of TF((0,1),(0,i))
__device__ __forceinline__ uint32_t threefry_bits(uint32_t i) {
    const uint32_t ks0 = 0u;
    const uint32_t ks1 = 1u;
    const uint32_t ks2 = 0x1BD11BDAu ^ ks0 ^ ks1;  // 0x1BD11BDB
    uint32_t x0 = 0u + ks0;
    uint32_t x1 = i + ks1;
#define TF_ROUND(r) { x0 += x1; x1 = rotl32(x1, (r)); x1 ^= x0; }
    TF_ROUND(13) TF_ROUND(15) TF_ROUND(26) TF_ROUND(6)
    x0 += ks1; x1 += ks2 + 1u;
    TF_ROUND(17) TF_ROUND(29) TF_ROUND(16) TF_ROUND(24)
    x0 += ks2; x1 += ks0 + 2u;
    TF_ROUND(13) TF_ROUND(15) TF_ROUND(26) TF_ROUND(6)
    x0 += ks0; x1 += ks1 + 3u;
    TF_ROUND(17) TF_ROUND(29) TF_ROUND(16) TF_ROUND(24)
    x0 += ks1; x1 += ks2 + 4u;
    TF_ROUND(13) TF_ROUND(15) TF_ROUND(26) TF_ROUND(6)
    x0 += ks2; x1 += ks0 + 5u;
#undef TF_ROUND
    return x0 ^ x1;
}

// fuse: coalesced grid/opacity reads; brick-scattered 4B table writes
__global__ __launch_bounds__(256)
void fuse_kernel(const float* __restrict__ grid, const float* __restrict__ opacity,
                 __half2* __restrict__ tab) {
    __shared__ float sh[256 * 9];
    const int t = threadIdx.x;
    const int base = blockIdx.x * 256;
    const float* gp = grid + (size_t)base * 9;
    #pragma unroll
    for (int i = 0; i < 9; ++i) {
        sh[i * 256 + t] = gp[i * 256 + t];
    }
    __syncthreads();
    float s = 0.f;
    #pragma unroll
    for (int c = 0; c < 9; ++c) s += sh[t * 9 + c];
    const int v = base + t;
    const int xq = v / (IDIM * IDIM);
    const int rem = v - xq * (IDIM * IDIM);
    const int yq = rem / IDIM;
    const int zq = rem - yq * IDIM;
    const int idx = (xq >> 1) * 73728 + ((xq & 1) << 3)
                  + (yq >> 1) * 768   + ((yq & 1) << 2)
                  + (zq >> 2) * 16    + (zq & 3);
    tab[idx] = __floats2half2_rn(s, opacity[v]);
}

// One ray per WAVE; 2 waves (rays) per 128-thread block; ZERO LDS.
// In-register bitonic sort (2 regs/lane). Compositing in rounds of 32
// samples with 2 LANES PER SAMPLE (even lane = x0 face, odd = x1 face,
// combined via shfl_xor(1)); wave-uniform early exit per round at cum>=10.
__global__ __launch_bounds__(128, 8)
void rf_kernel(const float* __restrict__ x, const float* __restrict__ d,
               const __half2* __restrict__ tab, float* __restrict__ out) {
    const int wave = threadIdx.x >> 6;
    const int lane = threadIdx.x & 63;
    const int r = blockIdx.x * 2 + wave;

    // --- ray setup ---
    const float ox = x[r * 3 + 0], oy = x[r * 3 + 1], oz = x[r * 3 + 2];
    const float dx = d[r * 3 + 0], dy = d[r * 3 + 1], dz = d[r * 3 + 2];
    const float inv_dx = 1.f / dx, inv_dy = 1.f / dy, inv_dz = 1.f / dz;
    const float INF = 7077888.f;  // 192^3
    const float BMAX = (float)(IDIM - 1);

    float tmin = -INF, tmax = INF;
    {
        float t0 = (0.f - ox) * inv_dx, t1 = (BMAX - ox) * inv_dx;
        tmin = fmaxf(tmin, fminf(t0, t1)); tmax = fminf(tmax, fmaxf(t0, t1));
        t0 = (0.f - oy) * inv_dy; t1 = (BMAX - oy) * inv_dy;
        tmin = fmaxf(tmin, fminf(t0, t1)); tmax = fminf(tmax, fmaxf(t0, t1));
        t0 = (0.f - oz) * inv_dz; t1 = (BMAX - oz) * inv_dz;
        tmin = fmaxf(tmin, fminf(t0, t1)); tmax = fminf(tmax, fmaxf(t0, t1));
    }

    // --- JAX-exact uniforms: this thread owns samples (lane) and (lane+64) ---
    const uint32_t i0 = (uint32_t)(r * NSAMP + lane);
    const uint32_t b0 = threefry_bits(i0);
    const uint32_t b1 = threefry_bits(i0 + 64u);
    float u0 = __uint_as_float((b0 >> 9) | 0x3f800000u) - 1.0f;
    float u1 = __uint_as_float((b1 >> 9) | 0x3f800000u) - 1.0f;
    u0 = fmaxf(0.f, u0);
    u1 = fmaxf(0.f, u1);
    float v0 = tmin + u0 * (tmax - tmin);
    float v1 = tmin + u1 * (tmax - tmin);

    // --- in-register wave-bitonic sort of 128 values (ascending) ---
#define BSTEP(J, K)                                                            \
    {                                                                          \
        const float p0 = __shfl_xor(v0, (J));                                  \
        const float p1 = __shfl_xor(v1, (J));                                  \
        const bool lower = (lane & (J)) == 0;                                  \
        const bool tm0 = (((lane) & (K)) == 0) == lower;                       \
        const bool tm1 = ((((lane) + 64) & (K)) == 0) == lower;                \
        v0 = tm0 ? fminf(v0, p0) : fmaxf(v0, p0);                              \
        v1 = tm1 ? fminf(v1, p1) : fmaxf(v1, p1);                              \
    }
    #pragma unroll
    for (int k = 2; k <= 64; k <<= 1) {
        #pragma unroll
        for (int j = k >> 1; j >= 1; j >>= 1) BSTEP(j, k)
    }
    {   // k = 128, j = 64: intra-thread exchange
        const float mn = fminf(v0, v1), mx = fmaxf(v0, v1);
        v0 = mn; v1 = mx;
    }
    #pragma unroll
    for (int j = 32; j >= 1; j >>= 1) BSTEP(j, 128)
#undef BSTEP
    // v0 = sorted[lane], v1 = sorted[lane + 64]

    // --- composite: 4 rounds of 32 samples, 2 lanes/sample, early exit ---
    const int odd = lane & 1;
    const int hs  = lane >> 1;            // sample slot within round
    float cumRay = 0.f, acc = 0.f;

    for (int k = 0; k < 4; ++k) {
        const int sk = k * 32 + hs;       // global sample index (0..127)
        const bool valid = (sk < NSAMP - 1);

        float ts, tn;
        if (k < 2) {
            ts = __shfl(v0, sk);
            const float tnv = __shfl(v0, (sk + 1 > 63) ? 63 : sk + 1);
            const float s64 = __shfl(v1, 0);
            tn = (sk == 63) ? s64 : tnv;
        } else {
            ts = __shfl(v1, sk - 64);
            const int ti = sk - 63;       // sorted[sk+1] index into v1
            tn = __shfl(v1, (ti > 63) ? 63 : ti);
        }

        // own-half trilinear: 4 corners (even: x0 face, odd: x1 face)
        const float px = ox + ts * dx;
        const float py = oy + ts * dy;
        const float pz = oz + ts * dz;
        int ix = (int)floorf(px); ix = ix < 0 ? 0 : (ix > IDIM - 2 ? IDIM - 2 : ix);
        int iy = (int)floorf(py); iy = iy < 0 ? 0 : (iy > IDIM - 2 ? IDIM - 2 : iy);
        int iz = (int)floorf(pz); iz = iz < 0 ? 0 : (iz > IDIM - 2 ? IDIM - 2 : iz);
        const float fx = px - (float)ix;
        const float fy = py - (float)iy;
        const float fz = pz - (float)iz;
        const float wxs = odd ? fx : (1.f - fx);
        const float wy0 = 1.f - fy, wy1 = fy;
        const float wz0 = 1.f - fz, wz1 = fz;
        const int xs = ix + odd;
        const int fs = (xs >> 1) * 73728 + ((xs & 1) << 3);
        const int g0 = (iy >> 1) * 768 + ((iy & 1) << 2);
        const int g1 = ((iy + 1) >> 1) * 768 + (((iy + 1) & 1) << 2);
        const int h0 = (iz >> 2) * 16 + (iz & 3);
        const int h1 = ((iz + 1) >> 2) * 16 + ((iz + 1) & 3);
        const float2 c00 = __half22float2(tab[fs + g0 + h0]);
        const float2 c01 = __half22float2(tab[fs + g0 + h1]);
        const float2 c10 = __half22float2(tab[fs + g1 + h0]);
        const float2 c11 = __half22float2(tab[fs + g1 + h1]);
        float hp = wxs * (wy0 * (wz0 * c00.x + wz1 * c01.x) +
                          wy1 * (wz0 * c10.x + wz1 * c11.x));
        float op = wxs * (wy0 * (wz0 * c00.y + wz1 * c01.y) +
                          wy1 * (wz0 * c10.y + wz1 * c11.y));
        const float hsv = hp + __shfl_xor(hp, 1);
        const float opv = op + __shfl_xor(op, 1);

        // scan input: only even lanes carry cur (odd = 0)
        const float cur = (valid && !odd) ? (tn - ts) * opv : 0.f;
        float incl = cur;
        #pragma unroll
        for (int off = 1; off < 64; off <<= 1) {
            const float tmp = __shfl_up(incl, off);
            if (lane >= off) incl += tmp;
        }
        if (valid && !odd) {
            const float excl = cumRay + incl - cur;
            const float color = 1.f / (1.f + __expf(-hsv));
            acc += __expf(-excl) * (1.f - __expf(-cur)) * color;
        }
        cumRay += __shfl(incl, 63);       // round total (uniform)
        if (cumRay >= 10.f) break;        // wave-uniform early exit
    }

    // --- wave reduction (odd lanes hold 0) ---
    #pragma unroll
    for (int off = 32; off > 0; off >>= 1) acc += __shfl_down(acc, off);
    if (lane == 0) out[r] = acc;
}

extern "C" void kernel_launch(void* const* d_in, const int* in_sizes, int n_in,
                              void* d_out, int out_size, void* d_ws, size_t ws_size,
                              hipStream_t stream) {
    const float* x       = (const float*)d_in[0];
    const float* d       = (const float*)d_in[1];
    const float* grid    = (const float*)d_in[2];
    const float* opacity = (const float*)d_in[3];
    float* out = (float*)d_out;

    fuse_kernel<<<NVOX / 256, 256, 0, stream>>>(grid, opacity, (__half2*)d_ws);
    rf_kernel<<<NRAYS / 2, 128, 0, stream>>>(x, d, (const __half2*)d_ws, out);
}

// Round 14
// 72.762 us; speedup vs baseline: 1.5631x; 1.0706x over previous
//
#include <hip/hip_runtime.h>
#include <hip/hip_fp16.h>
#include <cstdint>
#include <cstddef>

#define IDIM 192
#define NSAMP 128
#define NRAYS 16384
#define NVOX (IDIM * IDIM * IDIM)     // 7077888
#define NFUSE (NVOX / 256)            // 27648 fuse tiles
#define NSORTB (NRAYS / 4)            // 4096 sort blocks (4 rays each, 1/wave)
#define NBLK (NFUSE + NSORTB)         // 31744
#define SORT_PERIOD 7                 // 1 sort block per 7 (4096*7=28672<=NBLK)
#define SORT_LIM (NSORTB * SORT_PERIOD)

// Brick layout: 2x2x4 voxels = 16 entries x 4B = exactly one 64B cache line.
//   idx(x,y,z) = f(x) + g(y) + h(z)
//   f(x) = (x>>1)*73728 + (x&1)*8      (73728 = 96*48*16)
//   g(y) = (y>>1)*768   + (y&1)*4      (768   = 48*16)
//   h(z) = (z>>2)*16    + (z&3)

__device__ __forceinline__ uint32_t rotl32(uint32_t x, int r) {
    return (x << r) | (x >> (32 - r));
}

// JAX threefry2x32, key (0,1), partitionable path: bits(i) = x0 ^ x1 of TF((0,1),(0,i))
__device__ __forceinline__ uint32_t threefry_bits(uint32_t i) {
    const uint32_t ks0 = 0u;
    const uint32_t ks1 = 1u;
    const uint32_t ks2 = 0x1BD11BDAu ^ ks0 ^ ks1;  // 0x1BD11BDB
    uint32_t x0 = 0u + ks0;
    uint32_t x1 = i + ks1;
#define TF_ROUND(r) { x0 += x1; x1 = rotl32(x1, (r)); x1 ^= x0; }
    TF_ROUND(13) TF_ROUND(15) TF_ROUND(26) TF_ROUND(6)
    x0 += ks1; x1 += ks2 + 1u;
    TF_ROUND(17) TF_ROUND(29) TF_ROUND(16) TF_ROUND(24)
    x0 += ks2; x1 += ks0 + 2u;
    TF_ROUND(13) TF_ROUND(15) TF_ROUND(26) TF_ROUND(6)
    x0 += ks0; x1 += ks1 + 3u;
    TF_ROUND(17) TF_ROUND(29) TF_ROUND(16) TF_ROUND(24)
    x0 += ks1; x1 += ks2 + 4u;
    TF_ROUND(13) TF_ROUND(15) TF_ROUND(26) TF_ROUND(6)
    x0 += ks2; x1 += ks0 + 5u;
#undef TF_ROUND
    return x0 ^ x1;
}

// Mixed kernel 1: fuse tiles (memory-bound streaming) + 1-in-7 sort blocks
// (register/shuffle-only RNG + bitonic sort, zero LDS -> hides in the
// fuse blocks' memory stalls). Sort blocks write sorted samples to sts.
__global__ __launch_bounds__(256)
void prep_kernel(const float* __restrict__ grid, const float* __restrict__ opacity,
                 const float* __restrict__ x, const float* __restrict__ dvec,
                 __half2* __restrict__ tab, float* __restrict__ sts) {
    const int b = blockIdx.x;
    const bool is_sort = (b < SORT_LIM) && (b % SORT_PERIOD == 3);

    if (is_sort) {
        // ---- sortgen: 4 rays per block, one per wave; registers only ----
        const int q = b / SORT_PERIOD;          // 0..4095
        const int wv = threadIdx.x >> 6;
        const int lane = threadIdx.x & 63;
        const int r = q * 4 + wv;

        const float ox = x[r * 3 + 0], oy = x[r * 3 + 1], oz = x[r * 3 + 2];
        const float dx = dvec[r * 3 + 0], dy = dvec[r * 3 + 1], dz = dvec[r * 3 + 2];
        const float inv_dx = 1.f / dx, inv_dy = 1.f / dy, inv_dz = 1.f / dz;
        const float INF = 7077888.f;  // 192^3
        const float BMAX = (float)(IDIM - 1);

        float tmin = -INF, tmax = INF;
        {
            float t0 = (0.f - ox) * inv_dx, t1 = (BMAX - ox) * inv_dx;
            tmin = fmaxf(tmin, fminf(t0, t1)); tmax = fminf(tmax, fmaxf(t0, t1));
            t0 = (0.f - oy) * inv_dy; t1 = (BMAX - oy) * inv_dy;
            tmin = fmaxf(tmin, fminf(t0, t1)); tmax = fminf(tmax, fmaxf(t0, t1));
            t0 = (0.f - oz) * inv_dz; t1 = (BMAX - oz) * inv_dz;
            tmin = fmaxf(tmin, fminf(t0, t1)); tmax = fminf(tmax, fmaxf(t0, t1));
        }

        const uint32_t i0 = (uint32_t)(r * NSAMP + lane);
        const uint32_t b0 = threefry_bits(i0);
        const uint32_t b1 = threefry_bits(i0 + 64u);
        float u0 = __uint_as_float((b0 >> 9) | 0x3f800000u) - 1.0f;
        float u1 = __uint_as_float((b1 >> 9) | 0x3f800000u) - 1.0f;
        u0 = fmaxf(0.f, u0);
        u1 = fmaxf(0.f, u1);
        float v0 = tmin + u0 * (tmax - tmin);
        float v1 = tmin + u1 * (tmax - tmin);

#define BSTEP(J, K)                                                            \
        {                                                                      \
            const float p0 = __shfl_xor(v0, (J));                              \
            const float p1 = __shfl_xor(v1, (J));                              \
            const bool lower = (lane & (J)) == 0;                              \
            const bool tm0 = (((lane) & (K)) == 0) == lower;                   \
            const bool tm1 = ((((lane) + 64) & (K)) == 0) == lower;            \
            v0 = tm0 ? fminf(v0, p0) : fmaxf(v0, p0);                          \
            v1 = tm1 ? fminf(v1, p1) : fmaxf(v1, p1);                          \
        }
        #pragma unroll
        for (int k = 2; k <= 64; k <<= 1) {
            #pragma unroll
            for (int j = k >> 1; j >= 1; j >>= 1) BSTEP(j, k)
        }
        {
            const float mn = fminf(v0, v1), mx = fmaxf(v0, v1);
            v0 = mn; v1 = mx;
        }
        #pragma unroll
        for (int j = 32; j >= 1; j >>= 1) BSTEP(j, 128)
#undef BSTEP
        // v0 = sorted[lane], v1 = sorted[lane+64]; coalesced store
        sts[r * NSAMP + lane] = v0;
        sts[r * NSAMP + 64 + lane] = v1;
    } else {
        // ---- fuse tile: tab[brick(v)] = half2{sum_c grid[v][c], opacity[v]} ----
        __shared__ float sh[256 * 9];
        const int t = threadIdx.x;
        const int nsb = (b < SORT_LIM) ? (b + 3) / SORT_PERIOD : NSORTB;
        const int base = (b - nsb) * 256;
        const float* gp = grid + (size_t)base * 9;
        #pragma unroll
        for (int i = 0; i < 9; ++i) {
            sh[i * 256 + t] = gp[i * 256 + t];
        }
        __syncthreads();
        float s = 0.f;
        #pragma unroll
        for (int c = 0; c < 9; ++c) s += sh[t * 9 + c];
        const int v = base + t;
        const int xq = v / (IDIM * IDIM);
        const int rem = v - xq * (IDIM * IDIM);
        const int yq = rem / IDIM;
        const int zq = rem - yq * IDIM;
        const int idx = (xq >> 1) * 73728 + ((xq & 1) << 3)
                      + (yq >> 1) * 768   + ((yq & 1) << 2)
                      + (zq >> 2) * 16    + (zq & 3);
        tab[idx] = __floats2half2_rn(s, opacity[v]);
    }
}

// Kernel 2: gather + composite only. One ray per wave; sorted samples come
// from sts via two coalesced loads into (v0, v1). Rounds of 32 samples with
// 2 lanes/sample; wave-uniform early exit at cum >= 10.
__global__ __launch_bounds__(128, 8)
void rf_kernel(const float* __restrict__ x, const float* __restrict__ d,
               const __half2* __restrict__ tab, const float* __restrict__ sts,
               float* __restrict__ out) {
    const int wave = threadIdx.x >> 6;
    const int lane = threadIdx.x & 63;
    const int r = blockIdx.x * 2 + wave;

    const float ox = x[r * 3 + 0], oy = x[r * 3 + 1], oz = x[r * 3 + 2];
    const float dx = d[r * 3 + 0], dy = d[r * 3 + 1], dz = d[r * 3 + 2];

    const float v0 = sts[r * NSAMP + lane];        // sorted[lane]
    const float v1 = sts[r * NSAMP + 64 + lane];   // sorted[lane+64]

    const int odd = lane & 1;
    const int hs  = lane >> 1;
    float cumRay = 0.f, acc = 0.f;

    for (int k = 0; k < 4; ++k) {
        const int sk = k * 32 + hs;
        const bool valid = (sk < NSAMP - 1);

        float ts, tn;
        if (k < 2) {
            ts = __shfl(v0, sk);
            const float tnv = __shfl(v0, (sk + 1 > 63) ? 63 : sk + 1);
            const float s64 = __shfl(v1, 0);
            tn = (sk == 63) ? s64 : tnv;
        } else {
            ts = __shfl(v1, sk - 64);
            const int ti = sk - 63;
            tn = __shfl(v1, (ti > 63) ? 63 : ti);
        }

        const float px = ox + ts * dx;
        const float py = oy + ts * dy;
        const float pz = oz + ts * dz;
        int ix = (int)floorf(px); ix = ix < 0 ? 0 : (ix > IDIM - 2 ? IDIM - 2 : ix);
        int iy = (int)floorf(py); iy = iy < 0 ? 0 : (iy > IDIM - 2 ? IDIM - 2 : iy);
        int iz = (int)floorf(pz); iz = iz < 0 ? 0 : (iz > IDIM - 2 ? IDIM - 2 : iz);
        const float fx = px - (float)ix;
        const float fy = py - (float)iy;
        const float fz = pz - (float)iz;
        const float wxs = odd ? fx : (1.f - fx);
        const float wy0 = 1.f - fy, wy1 = fy;
        const float wz0 = 1.f - fz, wz1 = fz;
        const int xs = ix + odd;
        const int fs = (xs >> 1) * 73728 + ((xs & 1) << 3);
        const int g0 = (iy >> 1) * 768 + ((iy & 1) << 2);
        const int g1 = ((iy + 1) >> 1) * 768 + (((iy + 1) & 1) << 2);
        const int h0 = (iz >> 2) * 16 + (iz & 3);
        const int h1 = ((iz + 1) >> 2) * 16 + ((iz + 1) & 3);
        const float2 c00 = __half22float2(tab[fs + g0 + h0]);
        const float2 c01 = __half22float2(tab[fs + g0 + h1]);
        const float2 c10 = __half22float2(tab[fs + g1 + h0]);
        const float2 c11 = __half22float2(tab[fs + g1 + h1]);
        float hp = wxs * (wy0 * (wz0 * c00.x + wz1 * c01.x) +
                          wy1 * (wz0 * c10.x + wz1 * c11.x));
        float op = wxs * (wy0 * (wz0 * c00.y + wz1 * c01.y) +
                          wy1 * (wz0 * c10.y + wz1 * c11.y));
        const float hsv = hp + __shfl_xor(hp, 1);
        const float opv = op + __shfl_xor(op, 1);

        const float cur = (valid && !odd) ? (tn - ts) * opv : 0.f;
        float incl = cur;
        #pragma unroll
        for (int off = 1; off < 64; off <<= 1) {
            const float tmp = __shfl_up(incl, off);
            if (lane >= off) incl += tmp;
        }
        if (valid && !odd) {
            const float excl = cumRay + incl - cur;
            const float color = 1.f / (1.f + __expf(-hsv));
            acc += __expf(-excl) * (1.f - __expf(-cur)) * color;
        }
        cumRay += __shfl(incl, 63);
        if (cumRay >= 10.f) break;
    }

    #pragma unroll
    for (int off = 32; off > 0; off >>= 1) acc += __shfl_down(acc, off);
    if (lane == 0) out[r] = acc;
}

extern "C" void kernel_launch(void* const* d_in, const int* in_sizes, int n_in,
                              void* d_out, int out_size, void* d_ws, size_t ws_size,
                              hipStream_t stream) {
    const float* x       = (const float*)d_in[0];
    const float* d       = (const float*)d_in[1];
    const float* grid    = (const float*)d_in[2];
    const float* opacity = (const float*)d_in[3];
    float* out = (float*)d_out;

    __half2* tab = (__half2*)d_ws;
    float* sts = (float*)((char*)d_ws + (size_t)NVOX * sizeof(__half2));

    prep_kernel<<<NBLK, 256, 0, stream>>>(grid, opacity, x, d, tab, sts);
    rf_kernel<<<NRAYS / 2, 128, 0, stream>>>(x, d, tab, sts, out);
}